// Round 2
// baseline (486.293 us; speedup 1.0000x reference)
//
#include <hip/hip_runtime.h>
#include <hip/hip_bf16.h>
#include <stdint.h>

// CachedOPTAttention: B=4, T=1024, D=2048, H=32, HD=64, causal, idx=0.
// FP32 buffers; bf16-class error budget -> bf16 MFMA math inside.
//
// R4: fused QKV GEMM (N=6144, 1536 blocks vs 3x512), 128x64-tile O GEMM
// (1024 blocks), attention rebuilt as 512-thread QBLK=128 blocks with
// Qs->Ps LDS reuse and paired V-transpose writes.
//
// Buffer plan (ws usage <= 24MB; 32MB proven available):
//   d_out: [0,16)  xb = bf16(x)         (dead after QKV GEMM)
//          [16,32) qb = bf16((xWq+bq)/8)(dead after attention)
//          [32,96) cache f32            (final output, written by QKV GEMM)
//          O GEMM overwrites [0,32) with out f32 at the end.
//   d_ws:  [0,24)  WT3 = bf16 [Wq;Wk;Wv]^T  (dead after QKV GEMM)
//          then [0,8) WTo = bf16 Wo^T, [8,24) ctxb = bf16 attention out.

typedef __hip_bfloat16 bf16;
typedef unsigned short us;
typedef short s16x8 __attribute__((ext_vector_type(8)));
typedef float f32x4 __attribute__((ext_vector_type(4)));

#define T_SEQ   1024
#define D_MODEL 2048

__device__ inline us f2b(float f) {
    bf16 h = __float2bfloat16(f);
    return *(us*)&h;
}

typedef __attribute__((address_space(1))) const void gas_void;
typedef __attribute__((address_space(3))) void las_void;

__device__ inline void gl2lds16(const void* g, void* l) {
    // per-lane global src; LDS dest = wave-uniform base + lane*16
    __builtin_amdgcn_global_load_lds((gas_void*)g, (las_void*)l, 16, 0, 0);
}

// ---------------------------------------------------------------------------
// x[4096][2048] f32 -> bf16 (linear)
// ---------------------------------------------------------------------------
__global__ __launch_bounds__(256)
void cvtx_kernel(const float* __restrict__ x, us* __restrict__ xb)
{
    const size_t i = ((size_t)blockIdx.x * 256 + threadIdx.x) * 8;
    float4 a = *(const float4*)(x + i);
    float4 b = *(const float4*)(x + i + 4);
    union { uint4 u; us s[8]; } p;
    p.s[0] = f2b(a.x); p.s[1] = f2b(a.y); p.s[2] = f2b(a.z); p.s[3] = f2b(a.w);
    p.s[4] = f2b(b.x); p.s[5] = f2b(b.y); p.s[6] = f2b(b.z); p.s[7] = f2b(b.w);
    *(uint4*)(xb + i) = p.u;
}

// ---------------------------------------------------------------------------
// W[2048][2048] f32 (k-major) -> Wt + z*2048*2048: bf16 [N][K] (k contiguous).
// blockIdx.z selects among up to 3 weight matrices.
// ---------------------------------------------------------------------------
__global__ __launch_bounds__(256)
void wtrans_kernel(const float* __restrict__ W0, const float* __restrict__ W1,
                   const float* __restrict__ W2, us* __restrict__ Wt)
{
    __shared__ float tile[64][65];
    const int z = blockIdx.z;
    const float* W = (z == 0) ? W0 : (z == 1) ? W1 : W2;
    us* dst = Wt + (size_t)z * D_MODEL * D_MODEL;

    const int tid = threadIdx.x;
    const int k0 = blockIdx.y * 64, n0 = blockIdx.x * 64;

    const int rr = tid >> 4, cc = (tid & 15) * 4;
    #pragma unroll
    for (int i = 0; i < 4; ++i) {
        float4 v = *(const float4*)(W + (size_t)(k0 + rr + i * 16) * D_MODEL + n0 + cc);
        tile[rr + i * 16][cc]     = v.x;
        tile[rr + i * 16][cc + 1] = v.y;
        tile[rr + i * 16][cc + 2] = v.z;
        tile[rr + i * 16][cc + 3] = v.w;
    }
    __syncthreads();

    const int nr = tid >> 3, kc = (tid & 7) * 8;
    #pragma unroll
    for (int i = 0; i < 2; ++i) {
        const int n = nr + i * 32;
        union { uint4 u; us s[8]; } p;
        #pragma unroll
        for (int j = 0; j < 8; ++j) p.s[j] = f2b(tile[kc + j][n]);
        *(uint4*)(dst + (size_t)(n0 + n) * D_MODEL + k0 + kc) = p.u;
    }
}

// ---------------------------------------------------------------------------
// GEMM core (m97 structure): C[4096, N] = A(bf16) @ Bt^T + bias.
// Bt bf16 [N][K] k-contiguous. Tile 128 x (NI*32), BK=32, 4 waves (2x2),
// wave tile 64 x (NI*16), global_load_lds width-16 staging, linear LDS.
// MODE 0: f32 out (out0), bias b0.                       (O GEMM, NI=2)
// MODE 3: col routing by n0>>11: 0 -> bf16 qb=out0 scaled 1/8 (bias b0),
//         1/2 -> f32 cache=out1 slot 0/1 (bias b1/b2).   (QKV GEMM, NI=4)
// ---------------------------------------------------------------------------
template<int MODE, int NI>
__global__ __launch_bounds__(256)
void gemm_kernel(const us* __restrict__ A, const us* __restrict__ Bt,
                 const float* __restrict__ b0, const float* __restrict__ b1,
                 const float* __restrict__ b2,
                 float* __restrict__ out0, float* __restrict__ out1,
                 const int* __restrict__ idxp)
{
    __shared__ __align__(16) us As[128 * 32];
    __shared__ __align__(16) us Bs[NI * 32 * 32];

    const int tid  = threadIdx.x;
    const int wave = tid >> 6;
    const int lane = tid & 63;
    const int quad = lane >> 4;
    const int l15  = lane & 15;
    const int wm   = wave >> 1;
    const int wn   = wave & 1;
    const int m0   = blockIdx.y * 128;
    const int n0   = blockIdx.x * (NI * 32);

    constexpr int BCH = NI / 2;        // B 16-row chunks staged per wave
    const int ca   = wave * 2;         // A chunk index
    const int rowc = lane >> 2;
    const int kofs = (lane & 3) * 8;

    const us* aG = A  + (size_t)(m0 + ca * 16 + rowc) * D_MODEL + kofs;
    const us* bG = Bt + (size_t)(n0 + wave * BCH * 16 + rowc) * D_MODEL + kofs;
    us* aL = As + ca * 512;
    us* bL = Bs + wave * BCH * 512;

    f32x4 acc[4][NI];
    #pragma unroll
    for (int mi = 0; mi < 4; ++mi)
        #pragma unroll
        for (int ni = 0; ni < NI; ++ni) acc[mi][ni] = f32x4{0.f, 0.f, 0.f, 0.f};

    for (int k0 = 0; k0 < D_MODEL; k0 += 32) {
        gl2lds16(aG + k0,                aL);
        gl2lds16(aG + k0 + 16 * D_MODEL, aL + 512);
        if constexpr (BCH == 2) {
            gl2lds16(bG + k0,                bL);
            gl2lds16(bG + k0 + 16 * D_MODEL, bL + 512);
        } else {
            gl2lds16(bG + k0, bL);
        }
        __syncthreads();

        s16x8 af[4], bfr[NI];
        #pragma unroll
        for (int mi = 0; mi < 4; ++mi)
            af[mi] = *(const s16x8*)(As + (wm * 64 + mi * 16 + l15) * 32 + quad * 8);
        #pragma unroll
        for (int ni = 0; ni < NI; ++ni)
            bfr[ni] = *(const s16x8*)(Bs + (wn * NI * 16 + ni * 16 + l15) * 32 + quad * 8);
        #pragma unroll
        for (int mi = 0; mi < 4; ++mi)
            #pragma unroll
            for (int ni = 0; ni < NI; ++ni)
                acc[mi][ni] = __builtin_amdgcn_mfma_f32_16x16x32_bf16(af[mi], bfr[ni], acc[mi][ni], 0, 0, 0);
        __syncthreads();
    }

    const int reg = (MODE == 3) ? (n0 >> 11) : 0;   // uniform per block (n0 % 128 == 0)
    const float* bias = (MODE == 3) ? (reg == 0 ? b0 : (reg == 1 ? b1 : b2)) : b0;
    const int idx = (MODE == 3 && reg > 0) ? idxp[0] : 0;

    #pragma unroll
    for (int ni = 0; ni < NI; ++ni) {
        const int col = n0 + wn * NI * 16 + ni * 16 + l15;
        const int cl  = col & (D_MODEL - 1);
        const float bv = bias[cl];
        #pragma unroll
        for (int mi = 0; mi < 4; ++mi) {
            #pragma unroll
            for (int r = 0; r < 4; ++r) {
                const int m = m0 + wm * 64 + mi * 16 + quad * 4 + r;
                const float v = acc[mi][ni][r] + bv;
                if (MODE == 0) {
                    out0[(size_t)m * D_MODEL + cl] = v;
                } else {
                    if (reg == 0) {
                        // Q: bf16 with 1/sqrt(64) folded in (exact pow2)
                        ((us*)out0)[(size_t)m * D_MODEL + cl] = f2b(v * 0.125f);
                    } else {
                        const int b  = m >> 10;
                        const int tt = ((m & 1023) + idx) & 1023;
                        out1[((size_t)(b * 2 + (reg - 1)) * T_SEQ + tt) * D_MODEL + cl] = v;
                    }
                }
            }
        }
    }
}

// ---------------------------------------------------------------------------
// MFMA flash attention, QBLK=128: 512 thr = 8 waves, each wave owns 16 query
// rows. Per 64-key tile: stage K (row-major) + V (transposed, paired ushort2
// writes) from f32 cache; S=Q@K^T; in-register online softmax; P via LDS
// (reusing the dead Qs buffer); O += P@V^T. Fully-masked diagonal sub-tiles
// skipped per-wave. Q comes in bf16 pre-scaled by 1/8.
// ---------------------------------------------------------------------------
#define LDW  72
#define LDWV 70

__global__ __launch_bounds__(512, 6)
void attn_mfma_kernel(const us* __restrict__ q, const float* __restrict__ cache,
                      us* __restrict__ ctx)
{
    __shared__ __align__(16) us Qs[128 * LDW];   // Q tile; reused as Ps after hoist
    __shared__ __align__(16) us Ks[64 * LDW];    // Ks[key][d]
    __shared__ __align__(16) us Vt[64 * LDWV];   // Vt[d][key]

    const int tid  = threadIdx.x;
    const int wave = tid >> 6;          // 0..7
    const int lane = tid & 63;
    const int quad = lane >> 4;
    const int l15  = lane & 15;

    const int bh = blockIdx.x;          // b*32 + h
    const int b  = bh >> 5;
    const int h  = bh & 31;
    const int qt = 7 - blockIdx.y;      // query tile 0..7 (128 rows each)

    const float* kbase = cache + ((size_t)(b * 2 + 0) * T_SEQ) * D_MODEL + h * 64;
    const float* vbase = cache + ((size_t)(b * 2 + 1) * T_SEQ) * D_MODEL + h * 64;

    // ---- stage Q tile (128q x 64d), bf16 copy ----
    {
        const int qrow = tid >> 2;          // 0..127
        const int qp   = tid & 3;           // 16-d chunk
        const uint4* qg = (const uint4*)(q + (size_t)(b * T_SEQ + qt * 128 + qrow) * D_MODEL
                                           + h * 64 + qp * 16);
        uint4 q0 = qg[0], q1 = qg[1];
        *(uint4*)(Qs + qrow * LDW + qp * 16)     = q0;
        *(uint4*)(Qs + qrow * LDW + qp * 16 + 8) = q1;
    }
    __syncthreads();

    // hoist Q A-frags; Qs LDS is dead afterwards (becomes Ps)
    const s16x8 qf0 = *(const s16x8*)(Qs + (wave * 16 + l15) * LDW + quad * 8);
    const s16x8 qf1 = *(const s16x8*)(Qs + (wave * 16 + l15) * LDW + 32 + quad * 8);

    f32x4 oacc[4];
    #pragma unroll
    for (int t = 0; t < 4; ++t) oacc[t] = f32x4{0.f, 0.f, 0.f, 0.f};
    float m_run[4] = {-1e30f, -1e30f, -1e30f, -1e30f};
    float l_run[4] = {0.f, 0.f, 0.f, 0.f};

    const int nkt = 2 * qt + 2;

    // staging coords
    const int ksrow = tid >> 3;         // 0..63 (K row)
    const int kp8   = tid & 7;          // 8-d chunk
    const int vs    = tid >> 4;         // 0..31 (V key pair)
    const int vp4   = tid & 15;         // 4-d chunk

    for (int kt = 0; kt < nkt; ++kt) {
        __syncthreads();   // prior tile's frag reads done; safe to restage

        // ---- K: row-major bf16 ----
        {
            const float4* kg = (const float4*)(kbase + (size_t)(kt * 64 + ksrow) * D_MODEL + kp8 * 8);
            float4 k0 = kg[0], k1 = kg[1];
            union { uint4 u; us s[8]; } p;
            p.s[0] = f2b(k0.x); p.s[1] = f2b(k0.y); p.s[2] = f2b(k0.z); p.s[3] = f2b(k0.w);
            p.s[4] = f2b(k1.x); p.s[5] = f2b(k1.y); p.s[6] = f2b(k1.z); p.s[7] = f2b(k1.w);
            *(uint4*)(Ks + ksrow * LDW + kp8 * 8) = p.u;
        }
        // ---- V: transposed, 2 keys paired per ushort2 write ----
        {
            const float4 a = *(const float4*)(vbase + (size_t)(kt * 64 + 2 * vs) * D_MODEL + vp4 * 4);
            const float4 c = *(const float4*)(vbase + (size_t)(kt * 64 + 2 * vs + 1) * D_MODEL + vp4 * 4);
            const float av[4] = {a.x, a.y, a.z, a.w};
            const float cv[4] = {c.x, c.y, c.z, c.w};
            #pragma unroll
            for (int j = 0; j < 4; ++j) {
                ushort2 w; w.x = f2b(av[j]); w.y = f2b(cv[j]);
                *(ushort2*)(Vt + (vp4 * 4 + j) * LDWV + 2 * vs) = w;
            }
        }
        __syncthreads();

        const int kbr = kt * 64 - qt * 128;      // key base relative to q-block base
        if (kbr < wave * 16 + 16) {              // else: tile fully masked for this wave
            // ---- S = Q @ K^T : 16 queries x 64 keys ----
            f32x4 sacc[4];
            #pragma unroll
            for (int t = 0; t < 4; ++t) sacc[t] = f32x4{0.f, 0.f, 0.f, 0.f};
            #pragma unroll
            for (int t = 0; t < 4; ++t) {
                s16x8 kf0 = *(const s16x8*)(Ks + (t * 16 + l15) * LDW + quad * 8);
                s16x8 kf1 = *(const s16x8*)(Ks + (t * 16 + l15) * LDW + 32 + quad * 8);
                sacc[t] = __builtin_amdgcn_mfma_f32_16x16x32_bf16(qf0, kf0, sacc[t], 0, 0, 0);
                sacc[t] = __builtin_amdgcn_mfma_f32_16x16x32_bf16(qf1, kf1, sacc[t], 0, 0, 0);
            }

            // causal mask (only tiles straddling the diagonal for this wave)
            if (kbr + 63 > wave * 16) {
                #pragma unroll
                for (int t = 0; t < 4; ++t) {
                    const int keyl = kbr + t * 16 + l15;
                    #pragma unroll
                    for (int r = 0; r < 4; ++r) {
                        if (keyl > wave * 16 + quad * 4 + r) sacc[t][r] = -1e30f;
                    }
                }
            }

            // ---- online softmax (rows live in lane quads) ----
            float rmax[4];
            #pragma unroll
            for (int r = 0; r < 4; ++r)
                rmax[r] = fmaxf(fmaxf(sacc[0][r], sacc[1][r]), fmaxf(sacc[2][r], sacc[3][r]));
            #pragma unroll
            for (int off = 1; off < 16; off <<= 1) {
                #pragma unroll
                for (int r = 0; r < 4; ++r) rmax[r] = fmaxf(rmax[r], __shfl_xor(rmax[r], off, 16));
            }
            float alpha[4];
            #pragma unroll
            for (int r = 0; r < 4; ++r) {
                const float mnew = fmaxf(m_run[r], rmax[r]);
                alpha[r] = __expf(m_run[r] - mnew);
                m_run[r] = mnew;
            }
            float rsum[4] = {0.f, 0.f, 0.f, 0.f};
            #pragma unroll
            for (int t = 0; t < 4; ++t) {
                #pragma unroll
                for (int r = 0; r < 4; ++r) {
                    const float p = __expf(sacc[t][r] - m_run[r]);
                    sacc[t][r] = p;
                    rsum[r] += p;
                }
            }
            #pragma unroll
            for (int off = 1; off < 16; off <<= 1) {
                #pragma unroll
                for (int r = 0; r < 4; ++r) rsum[r] += __shfl_xor(rsum[r], off, 16);
            }
            #pragma unroll
            for (int r = 0; r < 4; ++r) l_run[r] = l_run[r] * alpha[r] + rsum[r];
            #pragma unroll
            for (int t = 0; t < 4; ++t) {
                #pragma unroll
                for (int r = 0; r < 4; ++r) oacc[t][r] *= alpha[r];
            }

            // ---- P -> LDS (per-wave private 16-row slab of reused Qs) ----
            #pragma unroll
            for (int t = 0; t < 4; ++t) {
                #pragma unroll
                for (int r = 0; r < 4; ++r)
                    Qs[(wave * 16 + quad * 4 + r) * LDW + t * 16 + l15] = f2b(sacc[t][r]);
            }
            // same-wave write->read: compiler orders LDS ops (may-alias) via lgkmcnt

            // ---- O += P @ V^T ----
            s16x8 pf0 = *(const s16x8*)(Qs + (wave * 16 + l15) * LDW + quad * 8);
            s16x8 pf1 = *(const s16x8*)(Qs + (wave * 16 + l15) * LDW + 32 + quad * 8);
            #pragma unroll
            for (int t = 0; t < 4; ++t) {
                s16x8 vf0 = *(const s16x8*)(Vt + (t * 16 + l15) * LDWV + quad * 8);
                s16x8 vf1 = *(const s16x8*)(Vt + (t * 16 + l15) * LDWV + 32 + quad * 8);
                oacc[t] = __builtin_amdgcn_mfma_f32_16x16x32_bf16(pf0, vf0, oacc[t], 0, 0, 0);
                oacc[t] = __builtin_amdgcn_mfma_f32_16x16x32_bf16(pf1, vf1, oacc[t], 0, 0, 0);
            }
        }
    }

    // ---- epilogue: ctx (bf16) = O / l ----
    float invl[4];
    #pragma unroll
    for (int r = 0; r < 4; ++r) invl[r] = 1.0f / l_run[r];
    #pragma unroll
    for (int r = 0; r < 4; ++r) {
        const int qrow = qt * 128 + wave * 16 + quad * 4 + r;
        us* orow = ctx + (size_t)(b * T_SEQ + qrow) * D_MODEL + h * 64;
        #pragma unroll
        for (int t = 0; t < 4; ++t) orow[t * 16 + l15] = f2b(oacc[t][r] * invl[r]);
    }
}

// ---------------------------------------------------------------------------
extern "C" void kernel_launch(void* const* d_in, const int* in_sizes, int n_in,
                              void* d_out, int out_size, void* d_ws, size_t ws_size,
                              hipStream_t stream)
{
    const float* x    = (const float*)d_in[0];
    const int*   idxp = (const int*)d_in[3];
    const float* Wq   = (const float*)d_in[4];
    const float* bq   = (const float*)d_in[5];
    const float* Wk   = (const float*)d_in[6];
    const float* bk   = (const float*)d_in[7];
    const float* Wv   = (const float*)d_in[8];
    const float* bv   = (const float*)d_in[9];
    const float* Wo   = (const float*)d_in[10];
    const float* bo   = (const float*)d_in[11];

    float* out      = (float*)d_out;
    us*    xb       = (us*)d_out;                                   // [0,16MB)
    us*    qb       = (us*)d_out + (size_t)8 * 1024 * 1024;         // [16,32MB)
    float* cacheOut = out + (size_t)4 * T_SEQ * D_MODEL;            // [32,96MB)

    us* WT3  = (us*)d_ws;                                           // [0,24MB)
    us* WTo  = (us*)d_ws;                                           // [0,8MB)  (after QKV)
    us* ctxb = (us*)d_ws + (size_t)4 * 1024 * 1024;                 // [8,24MB)

    const dim3 tb(256);

    cvtx_kernel<<<dim3(4096), tb, 0, stream>>>(x, xb);
    wtrans_kernel<<<dim3(32, 32, 3), tb, 0, stream>>>(Wq, Wk, Wv, WT3);

    // fused QKV: N = 6144
    gemm_kernel<3, 4><<<dim3(48, 32), tb, 0, stream>>>(
        xb, WT3, bq, bk, bv, (float*)qb, cacheOut, idxp);

    wtrans_kernel<<<dim3(32, 32, 1), tb, 0, stream>>>(Wo, Wo, Wo, WTo);

    attn_mfma_kernel<<<dim3(128, 8), dim3(512), 0, stream>>>(qb, cacheOut, ctxb);

    // O GEMM: 128x64 tiles -> 1024 blocks
    gemm_kernel<0, 2><<<dim3(32, 32), tb, 0, stream>>>(
        ctxb, WTo, bo, nullptr, nullptr, out, nullptr, nullptr);
}